// Round 19
// baseline (1291.475 us; speedup 1.0000x reference)
//
#include <hip/hip_runtime.h>
#include <hip/hip_bf16.h>

// ============================================================================
// PPO agent fused forward (round 19):
//  r18: 642us, issue-bound, gains flattening. Last zero-risk fat: the 8
//  per-layer __syncthreads are unnecessary (ACT is per-wave-private LDS;
//  params read-only after the one staging barrier). They force all 4 waves
//  to wait for the slowest at every layer boundary and suppress the natural
//  phase-drift that overlaps one wave's MFMA with another's VALU epilogue
//  (m114 co-scheduling). Weights stay L2-resident regardless of drift.
//  This round: identical to r18 minus per-layer barriers.
// ============================================================================

#define T_SZ 524288
#define GL 0.9405f   // GAMMA*LAM

typedef __attribute__((ext_vector_type(8))) short bf16x8;   // 8 bf16 (4 VGPRs)
typedef __attribute__((ext_vector_type(4))) float f32x4;

// ws layout (bf16 elements); weights in ntile/fragment-major layout (r13)
#define OFF_AW1T 0        // 256x64
#define OFF_AW2T 16384    // 256x256
#define OFF_AW3T 81920    // 32x256 (rows >=18 zero)
#define OFF_CW1T 90112    // 256x64
#define OFF_CW2T 106496   // 256x256
#define OFF_CW3T 172032   // 16x256 (rows >=1 zero)
#define W_ELEMS  176128
#define OFF_DELTAS_BYTES 352256

// k = p*32 + h*16 + w -> pos = p*32 + w*2 + h (applied to A and B alike)
__device__ __forceinline__ int perm_k(int k) {
  return (k & ~31) | ((k & 15) << 1) | ((k >> 4) & 1);
}

__device__ __forceinline__ unsigned pack2(float a, float b) {
  __hip_bfloat162 h = __float22bfloat162_rn(float2{a, b});   // v_cvt_pk_bf16_f32
  union { __hip_bfloat162 h2; unsigned u; } x;
  x.h2 = h;
  return x.u;
}

__device__ __forceinline__ void unpack2(unsigned u, float& a, float& b) {
  union { unsigned u; float f; } x, y;
  x.u = u << 16; y.u = u & 0xFFFF0000u;
  a = x.f; b = y.f;
}

// ACT stash accessor (stride 512B, 16B-granular XOR on row&7)
__device__ __forceinline__ void* act_at(void* base, int row, int colByte) {
  return (char*)base + row * 512 + (colByte ^ ((row & 7) << 4));
}

// ---------------------------------------------------------------------------
// X tile (16 rows x 64 fp32) -> 2 k-permuted bf16x8 frags per lane (no LDS).
__device__ __forceinline__ void load_x_frags(const float* __restrict__ src,
                                             int c, int q, bf16x8* xf) {
  const float* rp = src + (size_t)c * 64;
#pragma unroll
  for (int ks = 0; ks < 2; ++ks) {
    float4 a = *(const float4*)(rp + ks * 32 + 4 * q);
    float4 b = *(const float4*)(rp + ks * 32 + 4 * q + 16);
    unsigned u[4];
    u[0] = pack2(a.x, b.x); u[1] = pack2(a.y, b.y);
    u[2] = pack2(a.z, b.z); u[3] = pack2(a.w, b.w);
    xf[ks] = *(bf16x8*)u;
  }
}

// ---------------------------------------------------------------------------
// Linear(K->256)+bias+LN+ReLU. A-frags in regs (af[K/32]); B global
// fragment-major; params PF (LDS). Pass-1: per nt-pair MFMA -> bias -> s/ss
// -> pre-LN bf16 pair stash. Stats + srcLane broadcast; frag-build in regs
// (normalize+ReLU, 2xfma form) -> of[8]. of may alias af.
template<int K, int UNR>
__device__ __forceinline__ void layer_reg(const bf16x8* af,
    const char* __restrict__ W, const float* PF, char* ACT,
    int c, int q, int lane, bf16x8* of) {
  constexpr int NK = K / 32;
  float s[4] = {0, 0, 0, 0}, ss[4] = {0, 0, 0, 0};
#pragma unroll UNR
  for (int g = 0; g < 8; ++g) {          // nt pair (2g, 2g+1)
    const char* We = W + (size_t)(2 * g) * (K * 32);
    const char* Wo = We + (size_t)(K * 32);
    f32x4 e = {0.f, 0.f, 0.f, 0.f}, o = {0.f, 0.f, 0.f, 0.f};
#pragma unroll
    for (int ks = 0; ks < NK; ++ks) {
      bf16x8 be = *(const bf16x8*)(We + ks * 1024 + lane * 16);
      bf16x8 bo = *(const bf16x8*)(Wo + ks * 1024 + lane * 16);
      e = __builtin_amdgcn_mfma_f32_16x16x32_bf16(af[ks], be, e, 0, 0, 0);
      o = __builtin_amdgcn_mfma_f32_16x16x32_bf16(af[ks], bo, o, 0, 0, 0);
    }
    const float bbe = PF[2 * g * 16 + c];        // ds_read_b32
    const float bbo = PF[(2 * g + 1) * 16 + c];
#pragma unroll
    for (int r = 0; r < 4; ++r) {
      float ve = e[r] + bbe, vo = o[r] + bbo;
      s[r] += ve + vo; ss[r] += ve * ve + vo * vo;
      *(unsigned*)act_at(ACT, q * 4 + r, g * 64 + c * 4) = pack2(ve, vo);
    }
  }
  // stats over the 16 c-lanes (lane = q*16+c; xor m<16 flips c only)
#pragma unroll
  for (int m = 1; m < 16; m <<= 1) {
#pragma unroll
    for (int r = 0; r < 4; ++r) {
      s[r] += __shfl_xor(s[r], m, 64);
      ss[r] += __shfl_xor(ss[r], m, 64);
    }
  }
  float mean[4], rs[4];
#pragma unroll
  for (int r = 0; r < 4; ++r) {
    mean[r] = s[r] * (1.f / 256.f);
    float var = ss[r] * (1.f / 256.f) - mean[r] * mean[r];
    rs[r] = rsqrtf(var + 1e-5f);
  }
  // broadcast row-c stats: row c's stats live in lane q'=c>>2, slot r=c&3
  const int srcLane = ((c >> 2) << 4) + c;
  float mb[4], rb[4];
#pragma unroll
  for (int r = 0; r < 4; ++r) {
    mb[r] = __shfl(mean[r], srcLane, 64);
    rb[r] = __shfl(rs[r],   srcLane, 64);
  }
  const float m01 = (c & 1) ? mb[1] : mb[0], m23 = (c & 1) ? mb[3] : mb[2];
  const float r01 = (c & 1) ? rb[1] : rb[0], r23 = (c & 1) ? rb[3] : rb[2];
  const float mc = (c & 2) ? m23 : m01;
  const float rc = (c & 2) ? r23 : r01;
  const float mcr = -mc * rc;            // hoisted: (v-mc)*rc = fma(v, rc, mcr)
  // frag-build: read pre-LN pairs for row c, normalize+ReLU in regs -> of
  const float* GM = PF + 256;
  const float* BT = PF + 512;
#pragma unroll
  for (int ks = 0; ks < 8; ++ks) {
    uint4 dv = *(const uint4*)act_at(ACT, c, ks * 64 + q * 16);
    unsigned w[4];
    const unsigned* dp = (const unsigned*)&dv;
#pragma unroll
    for (int i = 0; i < 4; ++i) {
      const int n0 = ks * 32 + q * 4 + i;
      float v0, v1;
      unpack2(dp[i], v0, v1);
      float w0 = fmaxf(fmaf(fmaf(v0, rc, mcr), GM[n0],      BT[n0]),      0.f);
      float w1 = fmaxf(fmaf(fmaf(v1, rc, mcr), GM[n0 + 16], BT[n0 + 16]), 0.f);
      w[i] = pack2(w0, w1);
    }
    of[ks] = *(bf16x8*)w;
  }
}

// small final GEMM: NT ntiles, K=256, A-frags in regs, B fragment-major
template<int NT>
__device__ __forceinline__ void run_small_reg(const bf16x8* af,
    const char* __restrict__ W, int lane, f32x4* o) {
#pragma unroll
  for (int nt = 0; nt < NT; ++nt) o[nt] = (f32x4){0.f, 0.f, 0.f, 0.f};
#pragma unroll
  for (int nt = 0; nt < NT; ++nt) {
    const char* Wn = W + (size_t)nt * 8192;
#pragma unroll
    for (int ks = 0; ks < 8; ++ks) {
      bf16x8 b = *(const bf16x8*)(Wn + ks * 1024 + lane * 16);
      o[nt] = __builtin_amdgcn_mfma_f32_16x16x32_bf16(af[ks], b, o[nt], 0, 0, 0);
    }
  }
}

__device__ __forceinline__ void softmax_write(f32x4* acc3,
    const float* __restrict__ ab3, float* __restrict__ out,
    int grow0, int c, int q) {
  float b0 = ab3[c];
  float b1 = (c < 2) ? ab3[16 + c] : 0.f;
#pragma unroll
  for (int r = 0; r < 4; ++r) {
    float x0 = acc3[0][r] + b0;
    float x1 = (c < 2) ? (acc3[1][r] + b1) : -1e30f;
    float mx = fmaxf(x0, x1);
#pragma unroll
    for (int m = 1; m < 16; m <<= 1) mx = fmaxf(mx, __shfl_xor(mx, m, 64));
    float e0 = __expf(x0 - mx);
    float e1 = (c < 2) ? __expf(x1 - mx) : 0.f;
    float sm = e0 + e1;
#pragma unroll
    for (int m = 1; m < 16; m <<= 1) sm += __shfl_xor(sm, m, 64);
    float inv = 1.f / sm;
    int gr = grow0 + q * 4 + r;
    out[(size_t)gr * 20 + c] = e0 * inv;
    if (c < 2) out[(size_t)gr * 20 + 16 + c] = e1 * inv;
  }
}

// ---------------------------------------------------------------------------
// prep: ntile/fragment-major (r13-r18, verified). (n,k) of [N][K]:
// nt=n>>4, cc=n&15; kp=perm_k(k): ks=kp>>5, qq=(kp&31)>>3, e=kp&7
// -> elem = MO + nt*(16*K) + ks*512 + (qq*16+cc)*8 + e.
__device__ __forceinline__ int frag_idx(int mo, int K, int n, int k) {
  const int kp = perm_k(k);
  const int nt = n >> 4, cc = n & 15;
  const int ks = kp >> 5, w = kp & 31, qq = w >> 3, e = w & 7;
  return mo + nt * (16 * K) + ks * 512 + (qq * 16 + cc) * 8 + e;
}

__global__ void prep_weights(const float* __restrict__ aw1, const float* __restrict__ aw2,
                             const float* __restrict__ aw3, const float* __restrict__ cw1,
                             const float* __restrict__ cw2, const float* __restrict__ cw3,
                             __hip_bfloat16* __restrict__ wb) {
  int i = blockIdx.x * 256 + threadIdx.x;
  if (i >= W_ELEMS) return;
  float v; int dst;
  if (i < OFF_AW2T)      { int j = i;            int n = j >> 6, k = j & 63;  v = aw1[k * 256 + n];                 dst = frag_idx(OFF_AW1T, 64,  n, k); }
  else if (i < OFF_AW3T) { int j = i - OFF_AW2T; int n = j >> 8, k = j & 255; v = aw2[k * 256 + n];                 dst = frag_idx(OFF_AW2T, 256, n, k); }
  else if (i < OFF_CW1T) { int j = i - OFF_AW3T; int n = j >> 8, k = j & 255; v = (n < 18) ? aw3[k * 18 + n] : 0.f; dst = frag_idx(OFF_AW3T, 256, n, k); }
  else if (i < OFF_CW2T) { int j = i - OFF_CW1T; int n = j >> 6, k = j & 63;  v = cw1[k * 256 + n];                 dst = frag_idx(OFF_CW1T, 64,  n, k); }
  else if (i < OFF_CW3T) { int j = i - OFF_CW2T; int n = j >> 8, k = j & 255; v = cw2[k * 256 + n];                 dst = frag_idx(OFF_CW2T, 256, n, k); }
  else                   { int j = i - OFF_CW3T; int n = j >> 8, k = j & 255; v = (n == 0) ? cw3[k] : 0.f;          dst = frag_idx(OFF_CW3T, 256, n, k); }
  wb[dst] = __float2bfloat16(v);
}

// ---------------------------------------------------------------------------
__global__ __launch_bounds__(256, 2) void mlp_kernel(
    const float* __restrict__ states, const float* __restrict__ next_states,
    const float* __restrict__ rewards, const float* __restrict__ masks,
    const float* __restrict__ ab1, const float* __restrict__ ag1, const float* __restrict__ an1,
    const float* __restrict__ ab2, const float* __restrict__ ag2, const float* __restrict__ an2,
    const float* __restrict__ ab3,
    const float* __restrict__ cb1, const float* __restrict__ cg1, const float* __restrict__ cn1,
    const float* __restrict__ cb2, const float* __restrict__ cg2, const float* __restrict__ cn2,
    const float* __restrict__ cb3,
    const __hip_bfloat16* __restrict__ wbuf,
    float* __restrict__ deltas, float* __restrict__ out) {
  __shared__ char PB[12288];          // 4 LN param sets (bias|gam|bet) x 256 f32
  __shared__ char WV[4][8192];        // per-wave pre-LN stash (private per wave)
  const int tid = threadIdx.x;
  const int wave = tid >> 6, lane = tid & 63;
  const int c = lane & 15, q = lane >> 4;
  char* ACT = WV[wave];
  const char* W = (const char*)wbuf;
  const int base = blockIdx.x * 64 + wave * 16;   // 16 timesteps per wave

  // ---- stage params: wave w stages LN set w (bias@0, gam@1024, bet@2048) ----
  {
    const float* bsrc = (wave == 0) ? ab1 : (wave == 1) ? ab2 : (wave == 2) ? cb1 : cb2;
    const float* gsrc = (wave == 0) ? ag1 : (wave == 1) ? ag2 : (wave == 2) ? cg1 : cg2;
    const float* nsrc = (wave == 0) ? an1 : (wave == 1) ? an2 : (wave == 2) ? cn1 : cn2;
    char* dst = PB + wave * 3072;
    *(float4*)(dst + lane * 16)        = *(const float4*)(bsrc + lane * 4);
    *(float4*)(dst + 1024 + lane * 16) = *(const float4*)(gsrc + lane * 4);
    *(float4*)(dst + 2048 + lane * 16) = *(const float4*)(nsrc + lane * 4);
  }
  __syncthreads();   // the ONLY block barrier: params visible to all waves
  const float* PA1 = (const float*)(PB);
  const float* PA2 = (const float*)(PB + 3072);
  const float* PC1 = (const float*)(PB + 6144);
  const float* PC2 = (const float*)(PB + 9216);

  bf16x8 xf[2], af[8];

  // ---- X(states) -> regs (kept live across actor + critic) ----
  load_x_frags(states + (size_t)base * 64, c, q, xf);

  // ---- ACTOR(states) ---- (no block barriers: ACT is per-wave private)
  layer_reg<64, 4>(xf, W + OFF_AW1T * 2, PA1, ACT, c, q, lane, af);
  layer_reg<256, 2>(af, W + OFF_AW2T * 2, PA2, ACT, c, q, lane, af);
  {
    f32x4 p3[2];
    run_small_reg<2>(af, W + OFF_AW3T * 2, lane, p3);
    softmax_write(p3, ab3, out, base, c, q);
  }

  // ---- CRITIC(states) ---- (xf still live)
  layer_reg<64, 4>(xf, W + OFF_CW1T * 2, PC1, ACT, c, q, lane, af);
  layer_reg<256, 2>(af, W + OFF_CW2T * 2, PC2, ACT, c, q, lane, af);
  float vst[4];
  {
    f32x4 v[1];
    run_small_reg<1>(af, W + OFF_CW3T * 2, lane, v);
    const float b3 = cb3[0];
#pragma unroll
    for (int r = 0; r < 4; ++r) vst[r] = v[0][r] + b3;
  }

  // ---- CRITIC(next_states) ----
  load_x_frags(next_states + (size_t)base * 64, c, q, xf);
  layer_reg<64, 4>(xf, W + OFF_CW1T * 2, PC1, ACT, c, q, lane, af);
  layer_reg<256, 2>(af, W + OFF_CW2T * 2, PC2, ACT, c, q, lane, af);
  {
    f32x4 v[1];
    run_small_reg<1>(af, W + OFF_CW3T * 2, lane, v);
    const float b3 = cb3[0];
    if (c == 0) {
#pragma unroll
      for (int r = 0; r < 4; ++r) {
        const int gr = base + q * 4 + r;
        const float nv = v[0][r] + b3;
        out[(size_t)gr * 20 + 19] = vst[r];   // stash value; gae -> return
        deltas[gr] = rewards[gr] + 0.99f * nv * masks[gr] - vst[r];
      }
    }
  }
}

// ---------------------------------------------------------------------------
// GAE, wave-parallel: each wave owns a 512-elem chunk + 512-elem lookahead.
// Truncation: GL^512 ~ 2e-14. value stashed at out[:,19] -> returns.
__global__ __launch_bounds__(256) void gae_kernel(
    const float* __restrict__ deltas, const float* __restrict__ masks,
    float* __restrict__ out) {
  const int w = (blockIdx.x * blockDim.x + threadIdx.x) >> 6;  // 0..1023
  const int lane = threadIdx.x & 63;
  const int idx0 = w * 512 + lane * 16;

  float d[16], cf[16];
  if (idx0 < T_SZ) {
#pragma unroll
    for (int i = 0; i < 4; ++i) {
      *(float4*)(d + i * 4)  = *(const float4*)(deltas + idx0 + i * 4);
      *(float4*)(cf + i * 4) = *(const float4*)(masks + idx0 + i * 4);
    }
#pragma unroll
    for (int i = 0; i < 16; ++i) cf[i] *= GL;
  } else {
#pragma unroll
    for (int i = 0; i < 16; ++i) { d[i] = 0.f; cf[i] = 0.f; }
  }

  float A = 0.f, P = 1.f;
#pragma unroll
  for (int i = 15; i >= 0; --i) { A = d[i] + cf[i] * A; P *= cf[i]; }

  float As = A, Ps = P;
#pragma unroll
  for (int st = 1; st < 64; st <<= 1) {
    float An = __shfl_down(As, st, 64);
    float Pn = __shfl_down(Ps, st, 64);
    if (lane + st < 64) { As = As + Ps * An; Ps = Ps * Pn; }
  }
  float G = __shfl_down(As, 1, 64);
  if (lane == 63) G = 0.f;

  if (lane < 32) {
    float g = G;
#pragma unroll
    for (int i = 15; i >= 0; --i) {
      g = d[i] + cf[i] * g;
      const size_t j = (size_t)(idx0 + i);
      float val = out[j * 20 + 19];
      out[j * 20 + 18] = g;
      out[j * 20 + 19] = g + val;
    }
  }
}

// ---------------------------------------------------------------------------
extern "C" void kernel_launch(void* const* d_in, const int* in_sizes, int n_in,
                              void* d_out, int out_size, void* d_ws, size_t ws_size,
                              hipStream_t stream) {
  const float* states      = (const float*)d_in[0];
  const float* next_states = (const float*)d_in[1];
  const float* rewards     = (const float*)d_in[2];
  const float* masks       = (const float*)d_in[3];
  const float* aw1 = (const float*)d_in[4];
  const float* ab1 = (const float*)d_in[5];
  const float* ag1 = (const float*)d_in[6];
  const float* an1 = (const float*)d_in[7];
  const float* aw2 = (const float*)d_in[8];
  const float* ab2 = (const float*)d_in[9];
  const float* ag2 = (const float*)d_in[10];
  const float* an2 = (const float*)d_in[11];
  const float* aw3 = (const float*)d_in[12];
  const float* ab3 = (const float*)d_in[13];
  const float* cw1 = (const float*)d_in[14];
  const float* cb1 = (const float*)d_in[15];
  const float* cg1 = (const float*)d_in[16];
  const float* cn1 = (const float*)d_in[17];
  const float* cw2 = (const float*)d_in[18];
  const float* cb2 = (const float*)d_in[19];
  const float* cg2 = (const float*)d_in[20];
  const float* cn2 = (const float*)d_in[21];
  const float* cw3 = (const float*)d_in[22];
  const float* cb3 = (const float*)d_in[23];

  __hip_bfloat16* wbuf = (__hip_bfloat16*)d_ws;
  float* deltas = (float*)((char*)d_ws + OFF_DELTAS_BYTES);
  float* out = (float*)d_out;

  prep_weights<<<(W_ELEMS + 255) / 256, 256, 0, stream>>>(aw1, aw2, aw3, cw1, cw2, cw3, wbuf);
  mlp_kernel<<<T_SZ / 64, 256, 0, stream>>>(
      states, next_states, rewards, masks,
      ab1, ag1, an1, ab2, ag2, an2, ab3,
      cb1, cg1, cn1, cb2, cg2, cn2, cb3,
      wbuf, deltas, out);
  gae_kernel<<<256, 256, 0, stream>>>(deltas, masks, out);
}

// Round 20
// 641.761 us; speedup vs baseline: 2.0124x; 2.0124x over previous
//
#include <hip/hip_runtime.h>
#include <hip/hip_bf16.h>

// ============================================================================
// PPO agent fused forward (round 20 = revert to r18, the verified optimum):
//  r19 lesson: the per-layer __syncthreads are SCHEDULER FENCES. Removing
//  them let hipcc hoist next-layer weight loads across the LN epilogue ->
//  live-range explosion -> spill returned (VGPR 80->128, WRITE 70MB->1GB,
//  642->1291us). Reverted.
//  r18 state: 642us total; VGPR 80, occupancy 34% (3 waves/SIMD, jointly
//  LDS+VGPR-shadow capped), VALU 46% + MFMA 15.6% + LDS ~10% issue-occupied,
//  HBM 3%, WRITE 70MB (no spill). All structural levers to go past this
//  (barrier removal, deeper unrolls, register pipelining, occupancy forcing)
//  verifiably spill or are neutral -> practical floor of this structure.
// ============================================================================

#define T_SZ 524288
#define GL 0.9405f   // GAMMA*LAM

typedef __attribute__((ext_vector_type(8))) short bf16x8;   // 8 bf16 (4 VGPRs)
typedef __attribute__((ext_vector_type(4))) float f32x4;

// ws layout (bf16 elements); weights in ntile/fragment-major layout (r13)
#define OFF_AW1T 0        // 256x64
#define OFF_AW2T 16384    // 256x256
#define OFF_AW3T 81920    // 32x256 (rows >=18 zero)
#define OFF_CW1T 90112    // 256x64
#define OFF_CW2T 106496   // 256x256
#define OFF_CW3T 172032   // 16x256 (rows >=1 zero)
#define W_ELEMS  176128
#define OFF_DELTAS_BYTES 352256

// k = p*32 + h*16 + w -> pos = p*32 + w*2 + h (applied to A and B alike)
__device__ __forceinline__ int perm_k(int k) {
  return (k & ~31) | ((k & 15) << 1) | ((k >> 4) & 1);
}

__device__ __forceinline__ unsigned pack2(float a, float b) {
  __hip_bfloat162 h = __float22bfloat162_rn(float2{a, b});   // v_cvt_pk_bf16_f32
  union { __hip_bfloat162 h2; unsigned u; } x;
  x.h2 = h;
  return x.u;
}

__device__ __forceinline__ void unpack2(unsigned u, float& a, float& b) {
  union { unsigned u; float f; } x, y;
  x.u = u << 16; y.u = u & 0xFFFF0000u;
  a = x.f; b = y.f;
}

// ACT stash accessor (stride 512B, 16B-granular XOR on row&7)
__device__ __forceinline__ void* act_at(void* base, int row, int colByte) {
  return (char*)base + row * 512 + (colByte ^ ((row & 7) << 4));
}

// ---------------------------------------------------------------------------
// X tile (16 rows x 64 fp32) -> 2 k-permuted bf16x8 frags per lane (no LDS).
__device__ __forceinline__ void load_x_frags(const float* __restrict__ src,
                                             int c, int q, bf16x8* xf) {
  const float* rp = src + (size_t)c * 64;
#pragma unroll
  for (int ks = 0; ks < 2; ++ks) {
    float4 a = *(const float4*)(rp + ks * 32 + 4 * q);
    float4 b = *(const float4*)(rp + ks * 32 + 4 * q + 16);
    unsigned u[4];
    u[0] = pack2(a.x, b.x); u[1] = pack2(a.y, b.y);
    u[2] = pack2(a.z, b.z); u[3] = pack2(a.w, b.w);
    xf[ks] = *(bf16x8*)u;
  }
}

// ---------------------------------------------------------------------------
// Linear(K->256)+bias+LN+ReLU. A-frags in regs (af[K/32]); B global
// fragment-major; params PF (LDS). Pass-1: per nt-pair MFMA -> bias -> s/ss
// -> pre-LN bf16 pair stash. Stats + srcLane broadcast; frag-build in regs
// (normalize+ReLU, 2xfma form) -> of[8]. of may alias af.
template<int K, int UNR>
__device__ __forceinline__ void layer_reg(const bf16x8* af,
    const char* __restrict__ W, const float* PF, char* ACT,
    int c, int q, int lane, bf16x8* of) {
  constexpr int NK = K / 32;
  float s[4] = {0, 0, 0, 0}, ss[4] = {0, 0, 0, 0};
#pragma unroll UNR
  for (int g = 0; g < 8; ++g) {          // nt pair (2g, 2g+1)
    const char* We = W + (size_t)(2 * g) * (K * 32);
    const char* Wo = We + (size_t)(K * 32);
    f32x4 e = {0.f, 0.f, 0.f, 0.f}, o = {0.f, 0.f, 0.f, 0.f};
#pragma unroll
    for (int ks = 0; ks < NK; ++ks) {
      bf16x8 be = *(const bf16x8*)(We + ks * 1024 + lane * 16);
      bf16x8 bo = *(const bf16x8*)(Wo + ks * 1024 + lane * 16);
      e = __builtin_amdgcn_mfma_f32_16x16x32_bf16(af[ks], be, e, 0, 0, 0);
      o = __builtin_amdgcn_mfma_f32_16x16x32_bf16(af[ks], bo, o, 0, 0, 0);
    }
    const float bbe = PF[2 * g * 16 + c];        // ds_read_b32
    const float bbo = PF[(2 * g + 1) * 16 + c];
#pragma unroll
    for (int r = 0; r < 4; ++r) {
      float ve = e[r] + bbe, vo = o[r] + bbo;
      s[r] += ve + vo; ss[r] += ve * ve + vo * vo;
      *(unsigned*)act_at(ACT, q * 4 + r, g * 64 + c * 4) = pack2(ve, vo);
    }
  }
  // stats over the 16 c-lanes (lane = q*16+c; xor m<16 flips c only)
#pragma unroll
  for (int m = 1; m < 16; m <<= 1) {
#pragma unroll
    for (int r = 0; r < 4; ++r) {
      s[r] += __shfl_xor(s[r], m, 64);
      ss[r] += __shfl_xor(ss[r], m, 64);
    }
  }
  float mean[4], rs[4];
#pragma unroll
  for (int r = 0; r < 4; ++r) {
    mean[r] = s[r] * (1.f / 256.f);
    float var = ss[r] * (1.f / 256.f) - mean[r] * mean[r];
    rs[r] = rsqrtf(var + 1e-5f);
  }
  // broadcast row-c stats: row c's stats live in lane q'=c>>2, slot r=c&3
  const int srcLane = ((c >> 2) << 4) + c;
  float mb[4], rb[4];
#pragma unroll
  for (int r = 0; r < 4; ++r) {
    mb[r] = __shfl(mean[r], srcLane, 64);
    rb[r] = __shfl(rs[r],   srcLane, 64);
  }
  const float m01 = (c & 1) ? mb[1] : mb[0], m23 = (c & 1) ? mb[3] : mb[2];
  const float r01 = (c & 1) ? rb[1] : rb[0], r23 = (c & 1) ? rb[3] : rb[2];
  const float mc = (c & 2) ? m23 : m01;
  const float rc = (c & 2) ? r23 : r01;
  const float mcr = -mc * rc;            // hoisted: (v-mc)*rc = fma(v, rc, mcr)
  // frag-build: read pre-LN pairs for row c, normalize+ReLU in regs -> of
  const float* GM = PF + 256;
  const float* BT = PF + 512;
#pragma unroll
  for (int ks = 0; ks < 8; ++ks) {
    uint4 dv = *(const uint4*)act_at(ACT, c, ks * 64 + q * 16);
    unsigned w[4];
    const unsigned* dp = (const unsigned*)&dv;
#pragma unroll
    for (int i = 0; i < 4; ++i) {
      const int n0 = ks * 32 + q * 4 + i;
      float v0, v1;
      unpack2(dp[i], v0, v1);
      float w0 = fmaxf(fmaf(fmaf(v0, rc, mcr), GM[n0],      BT[n0]),      0.f);
      float w1 = fmaxf(fmaf(fmaf(v1, rc, mcr), GM[n0 + 16], BT[n0 + 16]), 0.f);
      w[i] = pack2(w0, w1);
    }
    of[ks] = *(bf16x8*)w;
  }
}

// small final GEMM: NT ntiles, K=256, A-frags in regs, B fragment-major
template<int NT>
__device__ __forceinline__ void run_small_reg(const bf16x8* af,
    const char* __restrict__ W, int lane, f32x4* o) {
#pragma unroll
  for (int nt = 0; nt < NT; ++nt) o[nt] = (f32x4){0.f, 0.f, 0.f, 0.f};
#pragma unroll
  for (int nt = 0; nt < NT; ++nt) {
    const char* Wn = W + (size_t)nt * 8192;
#pragma unroll
    for (int ks = 0; ks < 8; ++ks) {
      bf16x8 b = *(const bf16x8*)(Wn + ks * 1024 + lane * 16);
      o[nt] = __builtin_amdgcn_mfma_f32_16x16x32_bf16(af[ks], b, o[nt], 0, 0, 0);
    }
  }
}

__device__ __forceinline__ void softmax_write(f32x4* acc3,
    const float* __restrict__ ab3, float* __restrict__ out,
    int grow0, int c, int q) {
  float b0 = ab3[c];
  float b1 = (c < 2) ? ab3[16 + c] : 0.f;
#pragma unroll
  for (int r = 0; r < 4; ++r) {
    float x0 = acc3[0][r] + b0;
    float x1 = (c < 2) ? (acc3[1][r] + b1) : -1e30f;
    float mx = fmaxf(x0, x1);
#pragma unroll
    for (int m = 1; m < 16; m <<= 1) mx = fmaxf(mx, __shfl_xor(mx, m, 64));
    float e0 = __expf(x0 - mx);
    float e1 = (c < 2) ? __expf(x1 - mx) : 0.f;
    float sm = e0 + e1;
#pragma unroll
    for (int m = 1; m < 16; m <<= 1) sm += __shfl_xor(sm, m, 64);
    float inv = 1.f / sm;
    int gr = grow0 + q * 4 + r;
    out[(size_t)gr * 20 + c] = e0 * inv;
    if (c < 2) out[(size_t)gr * 20 + 16 + c] = e1 * inv;
  }
}

// ---------------------------------------------------------------------------
// prep: ntile/fragment-major (r13-r18, verified). (n,k) of [N][K]:
// nt=n>>4, cc=n&15; kp=perm_k(k): ks=kp>>5, qq=(kp&31)>>3, e=kp&7
// -> elem = MO + nt*(16*K) + ks*512 + (qq*16+cc)*8 + e.
__device__ __forceinline__ int frag_idx(int mo, int K, int n, int k) {
  const int kp = perm_k(k);
  const int nt = n >> 4, cc = n & 15;
  const int ks = kp >> 5, w = kp & 31, qq = w >> 3, e = w & 7;
  return mo + nt * (16 * K) + ks * 512 + (qq * 16 + cc) * 8 + e;
}

__global__ void prep_weights(const float* __restrict__ aw1, const float* __restrict__ aw2,
                             const float* __restrict__ aw3, const float* __restrict__ cw1,
                             const float* __restrict__ cw2, const float* __restrict__ cw3,
                             __hip_bfloat16* __restrict__ wb) {
  int i = blockIdx.x * 256 + threadIdx.x;
  if (i >= W_ELEMS) return;
  float v; int dst;
  if (i < OFF_AW2T)      { int j = i;            int n = j >> 6, k = j & 63;  v = aw1[k * 256 + n];                 dst = frag_idx(OFF_AW1T, 64,  n, k); }
  else if (i < OFF_AW3T) { int j = i - OFF_AW2T; int n = j >> 8, k = j & 255; v = aw2[k * 256 + n];                 dst = frag_idx(OFF_AW2T, 256, n, k); }
  else if (i < OFF_CW1T) { int j = i - OFF_AW3T; int n = j >> 8, k = j & 255; v = (n < 18) ? aw3[k * 18 + n] : 0.f; dst = frag_idx(OFF_AW3T, 256, n, k); }
  else if (i < OFF_CW2T) { int j = i - OFF_CW1T; int n = j >> 6, k = j & 63;  v = cw1[k * 256 + n];                 dst = frag_idx(OFF_CW1T, 64,  n, k); }
  else if (i < OFF_CW3T) { int j = i - OFF_CW2T; int n = j >> 8, k = j & 255; v = cw2[k * 256 + n];                 dst = frag_idx(OFF_CW2T, 256, n, k); }
  else                   { int j = i - OFF_CW3T; int n = j >> 8, k = j & 255; v = (n == 0) ? cw3[k] : 0.f;          dst = frag_idx(OFF_CW3T, 256, n, k); }
  wb[dst] = __float2bfloat16(v);
}

// ---------------------------------------------------------------------------
__global__ __launch_bounds__(256, 2) void mlp_kernel(
    const float* __restrict__ states, const float* __restrict__ next_states,
    const float* __restrict__ rewards, const float* __restrict__ masks,
    const float* __restrict__ ab1, const float* __restrict__ ag1, const float* __restrict__ an1,
    const float* __restrict__ ab2, const float* __restrict__ ag2, const float* __restrict__ an2,
    const float* __restrict__ ab3,
    const float* __restrict__ cb1, const float* __restrict__ cg1, const float* __restrict__ cn1,
    const float* __restrict__ cb2, const float* __restrict__ cg2, const float* __restrict__ cn2,
    const float* __restrict__ cb3,
    const __hip_bfloat16* __restrict__ wbuf,
    float* __restrict__ deltas, float* __restrict__ out) {
  __shared__ char PB[12288];          // 4 LN param sets (bias|gam|bet) x 256 f32
  __shared__ char WV[4][8192];        // per-wave pre-LN stash
  const int tid = threadIdx.x;
  const int wave = tid >> 6, lane = tid & 63;
  const int c = lane & 15, q = lane >> 4;
  char* ACT = WV[wave];
  const char* W = (const char*)wbuf;
  const int base = blockIdx.x * 64 + wave * 16;   // 16 timesteps per wave

  // ---- stage params: wave w stages LN set w (bias@0, gam@1024, bet@2048) ----
  {
    const float* bsrc = (wave == 0) ? ab1 : (wave == 1) ? ab2 : (wave == 2) ? cb1 : cb2;
    const float* gsrc = (wave == 0) ? ag1 : (wave == 1) ? ag2 : (wave == 2) ? cg1 : cg2;
    const float* nsrc = (wave == 0) ? an1 : (wave == 1) ? an2 : (wave == 2) ? cn1 : cn2;
    char* dst = PB + wave * 3072;
    *(float4*)(dst + lane * 16)        = *(const float4*)(bsrc + lane * 4);
    *(float4*)(dst + 1024 + lane * 16) = *(const float4*)(gsrc + lane * 4);
    *(float4*)(dst + 2048 + lane * 16) = *(const float4*)(nsrc + lane * 4);
  }
  __syncthreads();
  const float* PA1 = (const float*)(PB);
  const float* PA2 = (const float*)(PB + 3072);
  const float* PC1 = (const float*)(PB + 6144);
  const float* PC2 = (const float*)(PB + 9216);

  bf16x8 xf[2], af[8];

  // ---- X(states) -> regs (kept live across actor + critic) ----
  load_x_frags(states + (size_t)base * 64, c, q, xf);

  // ---- ACTOR(states) ----
  layer_reg<64, 4>(xf, W + OFF_AW1T * 2, PA1, ACT, c, q, lane, af);
  __syncthreads();
  layer_reg<256, 2>(af, W + OFF_AW2T * 2, PA2, ACT, c, q, lane, af);
  __syncthreads();
  {
    f32x4 p3[2];
    run_small_reg<2>(af, W + OFF_AW3T * 2, lane, p3);
    softmax_write(p3, ab3, out, base, c, q);
  }
  __syncthreads();

  // ---- CRITIC(states) ---- (xf still live)
  layer_reg<64, 4>(xf, W + OFF_CW1T * 2, PC1, ACT, c, q, lane, af);
  __syncthreads();
  layer_reg<256, 2>(af, W + OFF_CW2T * 2, PC2, ACT, c, q, lane, af);
  __syncthreads();
  float vst[4];
  {
    f32x4 v[1];
    run_small_reg<1>(af, W + OFF_CW3T * 2, lane, v);
    const float b3 = cb3[0];
#pragma unroll
    for (int r = 0; r < 4; ++r) vst[r] = v[0][r] + b3;
  }
  __syncthreads();

  // ---- CRITIC(next_states) ----
  load_x_frags(next_states + (size_t)base * 64, c, q, xf);
  layer_reg<64, 4>(xf, W + OFF_CW1T * 2, PC1, ACT, c, q, lane, af);
  __syncthreads();
  layer_reg<256, 2>(af, W + OFF_CW2T * 2, PC2, ACT, c, q, lane, af);
  __syncthreads();
  {
    f32x4 v[1];
    run_small_reg<1>(af, W + OFF_CW3T * 2, lane, v);
    const float b3 = cb3[0];
    if (c == 0) {
#pragma unroll
      for (int r = 0; r < 4; ++r) {
        const int gr = base + q * 4 + r;
        const float nv = v[0][r] + b3;
        out[(size_t)gr * 20 + 19] = vst[r];   // stash value; gae -> return
        deltas[gr] = rewards[gr] + 0.99f * nv * masks[gr] - vst[r];
      }
    }
  }
}

// ---------------------------------------------------------------------------
// GAE, wave-parallel: each wave owns a 512-elem chunk + 512-elem lookahead.
// Truncation: GL^512 ~ 2e-14. value stashed at out[:,19] -> returns.
__global__ __launch_bounds__(256) void gae_kernel(
    const float* __restrict__ deltas, const float* __restrict__ masks,
    float* __restrict__ out) {
  const int w = (blockIdx.x * blockDim.x + threadIdx.x) >> 6;  // 0..1023
  const int lane = threadIdx.x & 63;
  const int idx0 = w * 512 + lane * 16;

  float d[16], cf[16];
  if (idx0 < T_SZ) {
#pragma unroll
    for (int i = 0; i < 4; ++i) {
      *(float4*)(d + i * 4)  = *(const float4*)(deltas + idx0 + i * 4);
      *(float4*)(cf + i * 4) = *(const float4*)(masks + idx0 + i * 4);
    }
#pragma unroll
    for (int i = 0; i < 16; ++i) cf[i] *= GL;
  } else {
#pragma unroll
    for (int i = 0; i < 16; ++i) { d[i] = 0.f; cf[i] = 0.f; }
  }

  float A = 0.f, P = 1.f;
#pragma unroll
  for (int i = 15; i >= 0; --i) { A = d[i] + cf[i] * A; P *= cf[i]; }

  float As = A, Ps = P;
#pragma unroll
  for (int st = 1; st < 64; st <<= 1) {
    float An = __shfl_down(As, st, 64);
    float Pn = __shfl_down(Ps, st, 64);
    if (lane + st < 64) { As = As + Ps * An; Ps = Ps * Pn; }
  }
  float G = __shfl_down(As, 1, 64);
  if (lane == 63) G = 0.f;

  if (lane < 32) {
    float g = G;
#pragma unroll
    for (int i = 15; i >= 0; --i) {
      g = d[i] + cf[i] * g;
      const size_t j = (size_t)(idx0 + i);
      float val = out[j * 20 + 19];
      out[j * 20 + 18] = g;
      out[j * 20 + 19] = g + val;
    }
  }
}

// ---------------------------------------------------------------------------
extern "C" void kernel_launch(void* const* d_in, const int* in_sizes, int n_in,
                              void* d_out, int out_size, void* d_ws, size_t ws_size,
                              hipStream_t stream) {
  const float* states      = (const float*)d_in[0];
  const float* next_states = (const float*)d_in[1];
  const float* rewards     = (const float*)d_in[2];
  const float* masks       = (const float*)d_in[3];
  const float* aw1 = (const float*)d_in[4];
  const float* ab1 = (const float*)d_in[5];
  const float* ag1 = (const float*)d_in[6];
  const float* an1 = (const float*)d_in[7];
  const float* aw2 = (const float*)d_in[8];
  const float* ab2 = (const float*)d_in[9];
  const float* ag2 = (const float*)d_in[10];
  const float* an2 = (const float*)d_in[11];
  const float* aw3 = (const float*)d_in[12];
  const float* ab3 = (const float*)d_in[13];
  const float* cw1 = (const float*)d_in[14];
  const float* cb1 = (const float*)d_in[15];
  const float* cg1 = (const float*)d_in[16];
  const float* cn1 = (const float*)d_in[17];
  const float* cw2 = (const float*)d_in[18];
  const float* cb2 = (const float*)d_in[19];
  const float* cg2 = (const float*)d_in[20];
  const float* cn2 = (const float*)d_in[21];
  const float* cw3 = (const float*)d_in[22];
  const float* cb3 = (const float*)d_in[23];

  __hip_bfloat16* wbuf = (__hip_bfloat16*)d_ws;
  float* deltas = (float*)((char*)d_ws + OFF_DELTAS_BYTES);
  float* out = (float*)d_out;

  prep_weights<<<(W_ELEMS + 255) / 256, 256, 0, stream>>>(aw1, aw2, aw3, cw1, cw2, cw3, wbuf);
  mlp_kernel<<<T_SZ / 64, 256, 0, stream>>>(
      states, next_states, rewards, masks,
      ab1, ag1, an1, ab2, ag2, an2, ab3,
      cb1, cg1, cn1, cb2, cg2, cn2, cb3,
      wbuf, deltas, out);
  gae_kernel<<<256, 256, 0, stream>>>(deltas, masks, out);
}